// Round 3
// baseline (187.721 us; speedup 1.0000x reference)
//
#include <hip/hip_runtime.h>

#define NEGV -10000.0f

typedef _Float16 f16x8 __attribute__((ext_vector_type(8)));
typedef _Float16 f16x2 __attribute__((ext_vector_type(2)));
typedef float floatx4 __attribute__((ext_vector_type(4)));

// key (0..319) -> source sequence row. keys 0..63 local to query block nblk,
// keys 64..319 are the 256 global positions {0,61,62,63}+64j.
__device__ __forceinline__ int src_row(int key, int nblk) {
    if (key < 64) return nblk * 64 + key;
    int g = key - 64;
    int p = g & 3;
    return (g >> 2) * 64 + (p ? (60 + p) : 0);
}

__global__ __launch_bounds__(256, 4)
void sparse_attn_kernel(const float* __restrict__ Q, const float* __restrict__ K,
                        const float* __restrict__ V, const float* __restrict__ M,
                        float* __restrict__ O)
{
    // XCD swizzle: blockIdx%8 = XCD (dispatch heuristic); give each XCD 4 whole
    // heads so global K/V gather rows (128 KB/head) stay hot in that XCD's L2.
    const int x    = blockIdx.x;
    const int bh   = (x & 7) * 4 + ((x >> 3) >> 6);   // 0..31
    const int nblk = (x >> 3) & 63;                   // query block in head
    const int b    = bh >> 4;

    const size_t hoff = (size_t)bh * (4096 * 64);
    const float* Qh = Q + hoff;
    const float* Kh = K + hoff;
    const float* Vh = V + hoff;
    float*       Oh = O + hoff;
    const float* Mb = M + (size_t)b * 4096;

    // 40960 B total -> 4 blocks/CU. K fragment image: 40 slabs (20 key-tiles x
    // 2 k-chunks) of 1024B; slab s, lane l at elem s*512 + l*8. After QK the
    // whole region is reused: P frags [0,10240), VT frags [10240,20480).
    __shared__ _Float16 smem[20480];
    _Float16* Pbase  = smem;
    _Float16* VTbase = smem + 10240;

    const int tid  = threadIdx.x;
    const int lane = tid & 63;
    const int wv   = tid >> 6;          // wave -> query rows wv*16..+15
    const int m    = lane & 15;
    const int quad = lane >> 4;
    const int cg   = tid & 15;          // V staging: column granule (4 floats)
    const int psub = tid >> 4;          // V staging: row-pair sub-index

    // ---- mask additive terms -> registers (folded into MFMA C init later) ----
    float mreg[20];
    #pragma unroll
    for (int t = 0; t < 20; ++t) {
        int key = t * 16 + m;
        mreg[t] = (Mb[src_row(key, nblk)] == 0.0f) ? NEGV : 0.0f;
    }

    // ---- Q fragments direct from global (fp16, no split) ----
    const int qrow = nblk * 64 + wv * 16 + m;
    f16x8 qf[2];
    #pragma unroll
    for (int c = 0; c < 2; ++c) {
        const float* src = Qh + (size_t)qrow * 64 + c * 32 + quad * 8;
        float4 f0 = *(const float4*)src;
        float4 f1 = *(const float4*)(src + 4);
        qf[c][0] = (_Float16)f0.x; qf[c][1] = (_Float16)f0.y;
        qf[c][2] = (_Float16)f0.z; qf[c][3] = (_Float16)f0.w;
        qf[c][4] = (_Float16)f1.x; qf[c][5] = (_Float16)f1.y;
        qf[c][6] = (_Float16)f1.z; qf[c][7] = (_Float16)f1.w;
    }

    // ---- stage K directly in B-fragment layout: wave-linear b128 writes ----
    #pragma unroll
    for (int it = 0; it < 10; ++it) {
        int S    = it * 256 + tid;                       // 16B slot id, 0..2559
        int row  = ((S >> 7) * 16) + (S & 15);           // slab>>1 = t
        int col0 = ((S >> 6) & 1) * 32 + ((S & 63) >> 4) * 8;
        const float* src = Kh + (size_t)src_row(row, nblk) * 64 + col0;
        float4 f0 = *(const float4*)src;
        float4 f1 = *(const float4*)(src + 4);
        f16x8 o;
        o[0] = (_Float16)f0.x; o[1] = (_Float16)f0.y;
        o[2] = (_Float16)f0.z; o[3] = (_Float16)f0.w;
        o[4] = (_Float16)f1.x; o[5] = (_Float16)f1.y;
        o[6] = (_Float16)f1.z; o[7] = (_Float16)f1.w;
        *(f16x8*)(&smem[S * 8]) = o;
    }

    // ---- prefetch V chunk 0 (keys 0..159) as packed row-pairs ----
    f16x2 vpk[20];
    #pragma unroll
    for (int s = 0; s < 5; ++s) {
        int p = s * 16 + psub;                           // row pair 0..79
        const float4 f0 = *(const float4*)(Vh + (size_t)src_row(2 * p, nblk) * 64 + cg * 4);
        const float4 f1 = *(const float4*)(Vh + (size_t)src_row(2 * p + 1, nblk) * 64 + cg * 4);
        vpk[s*4+0][0] = (_Float16)f0.x; vpk[s*4+0][1] = (_Float16)f1.x;
        vpk[s*4+1][0] = (_Float16)f0.y; vpk[s*4+1][1] = (_Float16)f1.y;
        vpk[s*4+2][0] = (_Float16)f0.z; vpk[s*4+2][1] = (_Float16)f1.z;
        vpk[s*4+3][0] = (_Float16)f0.w; vpk[s*4+3][1] = (_Float16)f1.w;
    }

    __syncthreads();   // B1: K image complete

    // ---- QK^T: mask pre-loaded into accumulator; 40 MFMA, conflict-free reads ----
    floatx4 acc[20];
    #pragma unroll
    for (int t = 0; t < 20; ++t) {
        float ma = mreg[t];
        acc[t][0] = ma; acc[t][1] = ma; acc[t][2] = ma; acc[t][3] = ma;
    }
    #pragma unroll
    for (int t = 0; t < 20; ++t) {
        #pragma unroll
        for (int c = 0; c < 2; ++c) {
            f16x8 kf = *(const f16x8*)(&smem[(t * 2 + c) * 512 + lane * 8]);
            acc[t] = __builtin_amdgcn_mfma_f32_16x16x32_f16(qf[c], kf, acc[t], 0, 0, 0);
        }
    }

    // ---- softmax over 320 keys (rows quad*4+r, cols t*16+m) ----
    float rmax[4] = {-3e38f, -3e38f, -3e38f, -3e38f};
    #pragma unroll
    for (int t = 0; t < 20; ++t)
        #pragma unroll
        for (int r = 0; r < 4; ++r)
            rmax[r] = fmaxf(rmax[r], acc[t][r]);
    #pragma unroll
    for (int off = 8; off >= 1; off >>= 1)
        #pragma unroll
        for (int r = 0; r < 4; ++r)
            rmax[r] = fmaxf(rmax[r], __shfl_xor(rmax[r], off, 64));
    float rsum[4] = {0.f, 0.f, 0.f, 0.f};
    #pragma unroll
    for (int t = 0; t < 20; ++t)
        #pragma unroll
        for (int r = 0; r < 4; ++r) {
            float e = __expf(acc[t][r] - rmax[r]);
            acc[t][r] = e;                 // unnormalized; 1/sum applied at epilogue
            rsum[r] += e;
        }
    #pragma unroll
    for (int off = 8; off >= 1; off >>= 1)
        #pragma unroll
        for (int r = 0; r < 4; ++r)
            rsum[r] += __shfl_xor(rsum[r], off, 64);
    float rinv[4];
    #pragma unroll
    for (int r = 0; r < 4; ++r) rinv[r] = 1.0f / rsum[r];

    __syncthreads();   // B2: all QK reads of K image done

    // ---- chunk 0: write P frags (keys 0..159) + VT frags from registers ----
    #pragma unroll
    for (int tp = 0; tp < 10; ++tp) {
        int slab = wv * 5 + (tp >> 1);
        int qa   = (tp & 1) * 2 + (m >> 3);
        int jj   = m & 7;
        #pragma unroll
        for (int r = 0; r < 4; ++r)
            Pbase[slab * 512 + (qa * 16 + quad * 4 + r) * 8 + jj] = (_Float16)acc[tp][r];
    }
    #pragma unroll
    for (int s = 0; s < 5; ++s) {
        int rl  = 2 * (s * 16 + psub);                   // chunk-local even row
        int kcl = rl >> 5, qv = (rl & 31) >> 3, jj0 = rl & 7;
        #pragma unroll
        for (int e = 0; e < 4; ++e) {
            int col = cg * 4 + e;
            *(f16x2*)(&VTbase[((col >> 4) * 5 + kcl) * 512 + (qv * 16 + (col & 15)) * 8 + jj0]) =
                vpk[s * 4 + e];
        }
    }
    // issue V chunk-1 raw loads now; latency hides under PV0 MFMAs
    float4 vr0[5], vr1[5];
    #pragma unroll
    for (int s = 0; s < 5; ++s) {
        int p = (5 + s) * 16 + psub;                     // row pair 80..159
        vr0[s] = *(const float4*)(Vh + (size_t)src_row(2 * p, nblk) * 64 + cg * 4);
        vr1[s] = *(const float4*)(Vh + (size_t)src_row(2 * p + 1, nblk) * 64 + cg * 4);
    }

    __syncthreads();   // B3: P0/VT0 image complete

    floatx4 oacc[4] = {};
    #pragma unroll
    for (int kc = 0; kc < 5; ++kc) {
        f16x8 pf = *(const f16x8*)(&Pbase[(wv * 5 + kc) * 512 + lane * 8]);
        #pragma unroll
        for (int t = 0; t < 4; ++t) {
            f16x8 vf = *(const f16x8*)(&VTbase[(t * 5 + kc) * 512 + lane * 8]);
            oacc[t] = __builtin_amdgcn_mfma_f32_16x16x32_f16(pf, vf, oacc[t], 0, 0, 0);
        }
    }

    __syncthreads();   // B4: PV0 reads done, region reusable

    // ---- chunk 1: write P frags (keys 160..319) + VT frags from vr ----
    #pragma unroll
    for (int tp = 0; tp < 10; ++tp) {
        int slab = wv * 5 + (tp >> 1);
        int qa   = (tp & 1) * 2 + (m >> 3);
        int jj   = m & 7;
        #pragma unroll
        for (int r = 0; r < 4; ++r)
            Pbase[slab * 512 + (qa * 16 + quad * 4 + r) * 8 + jj] = (_Float16)acc[10 + tp][r];
    }
    #pragma unroll
    for (int s = 0; s < 5; ++s) {
        int rl  = 2 * ((5 + s) * 16 + psub) - 160;       // chunk-local even row
        int kcl = rl >> 5, qv = (rl & 31) >> 3, jj0 = rl & 7;
        const float4 f0 = vr0[s];
        const float4 f1 = vr1[s];
        f16x2 pk[4];
        pk[0][0] = (_Float16)f0.x; pk[0][1] = (_Float16)f1.x;
        pk[1][0] = (_Float16)f0.y; pk[1][1] = (_Float16)f1.y;
        pk[2][0] = (_Float16)f0.z; pk[2][1] = (_Float16)f1.z;
        pk[3][0] = (_Float16)f0.w; pk[3][1] = (_Float16)f1.w;
        #pragma unroll
        for (int e = 0; e < 4; ++e) {
            int col = cg * 4 + e;
            *(f16x2*)(&VTbase[((col >> 4) * 5 + kcl) * 512 + (qv * 16 + (col & 15)) * 8 + jj0]) =
                pk[e];
        }
    }

    __syncthreads();   // B5: P1/VT1 image complete

    #pragma unroll
    for (int kc = 0; kc < 5; ++kc) {
        f16x8 pf = *(const f16x8*)(&Pbase[(wv * 5 + kc) * 512 + lane * 8]);
        #pragma unroll
        for (int t = 0; t < 4; ++t) {
            f16x8 vf = *(const f16x8*)(&VTbase[(t * 5 + kc) * 512 + lane * 8]);
            oacc[t] = __builtin_amdgcn_mfma_f32_16x16x32_f16(pf, vf, oacc[t], 0, 0, 0);
        }
    }

    // ---- epilogue: apply 1/rowsum, store fp32 ----
    #pragma unroll
    for (int t = 0; t < 4; ++t)
        #pragma unroll
        for (int r = 0; r < 4; ++r)
            Oh[(size_t)(nblk * 64 + wv * 16 + quad * 4 + r) * 64 + t * 16 + m] =
                oacc[t][r] * rinv[r];
}

extern "C" void kernel_launch(void* const* d_in, const int* in_sizes, int n_in,
                              void* d_out, int out_size, void* d_ws, size_t ws_size,
                              hipStream_t stream) {
    const float* q    = (const float*)d_in[0];
    const float* k    = (const float*)d_in[1];
    const float* v    = (const float*)d_in[2];
    const float* mask = (const float*)d_in[3];
    float* out = (float*)d_out;
    (void)in_sizes; (void)n_in; (void)out_size; (void)d_ws; (void)ws_size;
    sparse_attn_kernel<<<2 * 16 * 64, 256, 0, stream>>>(q, k, v, mask, out);
}